// Round 1
// baseline (432.998 us; speedup 1.0000x reference)
//
#include <hip/hip_runtime.h>
#include <math.h>

#define N_NODES 50000
#define N_EDGES 800000
#define IN_DIM  128
#define OUT_DIM 64
#define LEAKY   0.01f

// ---------------------------------------------------------------------------
// float atomic max via CAS on the int view (values are never NaN here)
__device__ __forceinline__ void atomicMaxFloat(float* addr, float val) {
    int* ia = (int*)addr;
    int old = *ia;
    while (__int_as_float(old) < val) {
        int assumed = old;
        old = atomicCAS(ia, assumed, __float_as_int(val));
        if (old == assumed) break;
    }
}

// ---------------------------------------------------------------------------
// fill e_max with -inf
__global__ __launch_bounds__(256) void fill_neginf_kernel(float* __restrict__ p, int n) {
    int i = blockIdx.x * 256 + threadIdx.x;
    if (i < n) p[i] = -INFINITY;
}

// ---------------------------------------------------------------------------
// z = feat @ W  (one block of 64 threads per node row; thread d owns out-dim d)
// epilogue: az_src[row] = z_row . a[:64], az_dst[row] = z_row . a[64:]
__global__ __launch_bounds__(64) void proj_kernel(
        const float* __restrict__ feat, const float* __restrict__ W,
        const float* __restrict__ a,
        float* __restrict__ z, float* __restrict__ az_src, float* __restrict__ az_dst) {
    int row = blockIdx.x;
    int d   = threadIdx.x;            // 0..63
    __shared__ float fs[IN_DIM];
    fs[d]      = feat[row * IN_DIM + d];
    fs[d + 64] = feat[row * IN_DIM + d + 64];
    __syncthreads();
    float acc = 0.f;
#pragma unroll 8
    for (int k = 0; k < IN_DIM; ++k)
        acc += fs[k] * W[k * OUT_DIM + d];
    z[row * OUT_DIM + d] = acc;
    float s1 = acc * a[d];
    float s2 = acc * a[OUT_DIM + d];
    // 64-lane wave reduction
    for (int off = 32; off > 0; off >>= 1) {
        s1 += __shfl_down(s1, off, 64);
        s2 += __shfl_down(s2, off, 64);
    }
    if (d == 0) { az_src[row] = s1; az_dst[row] = s2; }
}

// ---------------------------------------------------------------------------
// per-edge score e = leaky_relu(az_src[src]+az_dst[dst]); scatter-max into e_max
__global__ __launch_bounds__(256) void edge_score_kernel(
        const int* __restrict__ src, const int* __restrict__ dst,
        const float* __restrict__ az_src, const float* __restrict__ az_dst,
        float* __restrict__ e_buf, float* __restrict__ e_max) {
    int i = blockIdx.x * 256 + threadIdx.x;
    if (i >= N_EDGES) return;
    int s = src[i], t = dst[i];
    float v = az_src[s] + az_dst[t];
    float e = v > 0.f ? v : LEAKY * v;
    e_buf[i] = e;
    atomicMaxFloat(&e_max[t], e);
}

// ---------------------------------------------------------------------------
// e_exp = exp(e - e_max[dst]); scatter-add into e_sum; overwrite e_buf with exp
__global__ __launch_bounds__(256) void edge_exp_kernel(
        const int* __restrict__ dst,
        float* __restrict__ e_buf, const float* __restrict__ e_max,
        float* __restrict__ e_sum) {
    int i = blockIdx.x * 256 + threadIdx.x;
    if (i >= N_EDGES) return;
    int t = dst[i];
    float ex = __expf(e_buf[i] - e_max[t]);
    e_buf[i] = ex;
    atomicAdd(&e_sum[t], ex);
}

// ---------------------------------------------------------------------------
// h[dst] += (e_exp/e_sum[dst]) * z[src]   — one thread per (edge, dim)
__global__ __launch_bounds__(256) void scatter_kernel(
        const int* __restrict__ src, const int* __restrict__ dst,
        const float* __restrict__ e_buf, const float* __restrict__ e_sum,
        const float* __restrict__ z, float* __restrict__ h) {
    int gid = blockIdx.x * 256 + threadIdx.x;   // up to 51.2M < 2^31
    if (gid >= N_EDGES * OUT_DIM) return;
    int e = gid >> 6;       // edge
    int d = gid & 63;       // dim
    int s = src[e], t = dst[e];
    float alpha = e_buf[e] / e_sum[t];
    atomicAdd(&h[t * OUT_DIM + d], alpha * z[s * OUT_DIM + d]);
}

// ---------------------------------------------------------------------------
extern "C" void kernel_launch(void* const* d_in, const int* in_sizes, int n_in,
                              void* d_out, int out_size, void* d_ws, size_t ws_size,
                              hipStream_t stream) {
    const float* feat = (const float*)d_in[0];
    const int*   src  = (const int*)  d_in[1];
    const int*   dst  = (const int*)  d_in[2];
    const float* W    = (const float*)d_in[3];
    const float* a    = (const float*)d_in[4];
    float* h = (float*)d_out;

    // workspace layout (floats)
    float* z      = (float*)d_ws;                    // N*64
    float* az_src = z      + (size_t)N_NODES * OUT_DIM;
    float* az_dst = az_src + N_NODES;
    float* e_max  = az_dst + N_NODES;
    float* e_sum  = e_max  + N_NODES;
    float* e_buf  = e_sum  + N_NODES;                // N_EDGES

    hipMemsetAsync(h,     0, sizeof(float) * (size_t)N_NODES * OUT_DIM, stream);
    hipMemsetAsync(e_sum, 0, sizeof(float) * N_NODES, stream);
    fill_neginf_kernel<<<(N_NODES + 255) / 256, 256, 0, stream>>>(e_max, N_NODES);

    proj_kernel<<<N_NODES, 64, 0, stream>>>(feat, W, a, z, az_src, az_dst);

    int eblocks = (N_EDGES + 255) / 256;
    edge_score_kernel<<<eblocks, 256, 0, stream>>>(src, dst, az_src, az_dst, e_buf, e_max);
    edge_exp_kernel<<<eblocks, 256, 0, stream>>>(dst, e_buf, e_max, e_sum);

    int sthreads = N_EDGES * OUT_DIM;
    scatter_kernel<<<(sthreads + 255) / 256, 256, 0, stream>>>(src, dst, e_buf, e_sum, z, h);
}

// Round 2
// 270.378 us; speedup vs baseline: 1.6015x; 1.6015x over previous
//
#include <hip/hip_runtime.h>
#include <math.h>

#define N_NODES 50000
#define N_EDGES 800000
#define IN_DIM  128
#define OUT_DIM 64
#define LEAKY   0.01f

#define SCAN_B   1024
#define SCAN_NB  ((N_NODES + SCAN_B - 1) / SCAN_B)   // 49

// ---------------------------------------------------------------------------
// z = feat @ W ; az_src/az_dst epilogue. 256 threads = 4 waves = 4 rows/block.
__global__ __launch_bounds__(256) void proj_kernel(
        const float* __restrict__ feat, const float* __restrict__ W,
        const float* __restrict__ a,
        float* __restrict__ z, float* __restrict__ az_src, float* __restrict__ az_dst) {
    int lane = threadIdx.x & 63;
    int w    = threadIdx.x >> 6;
    int row  = blockIdx.x * 4 + w;
    __shared__ float fs[4][IN_DIM];
    fs[w][lane]      = feat[(size_t)row * IN_DIM + lane];
    fs[w][lane + 64] = feat[(size_t)row * IN_DIM + lane + 64];
    // wave-private LDS slice; compiler inserts lgkmcnt waits
    float acc = 0.f;
#pragma unroll 8
    for (int k = 0; k < IN_DIM; ++k)
        acc += fs[w][k] * W[k * OUT_DIM + lane];
    z[(size_t)row * OUT_DIM + lane] = acc;
    float s1 = acc * a[lane];
    float s2 = acc * a[OUT_DIM + lane];
    for (int off = 32; off > 0; off >>= 1) {
        s1 += __shfl_down(s1, off, 64);
        s2 += __shfl_down(s2, off, 64);
    }
    if (lane == 0) { az_src[row] = s1; az_dst[row] = s2; }
}

// ---------------------------------------------------------------------------
// degree histogram
__global__ __launch_bounds__(256) void hist_kernel(
        const int* __restrict__ dst, int* __restrict__ counts) {
    int i = blockIdx.x * 256 + threadIdx.x;
    if (i < N_EDGES) atomicAdd(&counts[dst[i]], 1);
}

// ---------------------------------------------------------------------------
// scan step 1: per-block exclusive scan, block totals out
__global__ __launch_bounds__(SCAN_B) void scan1_kernel(
        const int* __restrict__ counts, int* __restrict__ offsets,
        int* __restrict__ blocksums) {
    __shared__ int s[SCAN_B];
    int i = blockIdx.x * SCAN_B + threadIdx.x;
    int v = (i < N_NODES) ? counts[i] : 0;
    s[threadIdx.x] = v;
    __syncthreads();
    for (int off = 1; off < SCAN_B; off <<= 1) {
        int t = (threadIdx.x >= off) ? s[threadIdx.x - off] : 0;
        __syncthreads();
        s[threadIdx.x] += t;
        __syncthreads();
    }
    if (i < N_NODES) offsets[i] = s[threadIdx.x] - v;     // exclusive within block
    if (threadIdx.x == SCAN_B - 1) blocksums[blockIdx.x] = s[SCAN_B - 1];
}

// scan step 2: exclusive scan of the 49 block totals (in place), one block
__global__ __launch_bounds__(64) void scan2_kernel(int* __restrict__ blocksums) {
    __shared__ int s[64];
    int tid = threadIdx.x;
    int v = (tid < SCAN_NB) ? blocksums[tid] : 0;
    s[tid] = v;
    __syncthreads();
    for (int off = 1; off < 64; off <<= 1) {
        int t = (tid >= off) ? s[tid - off] : 0;
        __syncthreads();
        s[tid] += t;
        __syncthreads();
    }
    if (tid < SCAN_NB) blocksums[tid] = s[tid] - v;       // exclusive
}

// scan step 3: add block offset; init cursor; seal offsets[N]
__global__ __launch_bounds__(SCAN_B) void scan3_kernel(
        int* __restrict__ offsets, int* __restrict__ cursor,
        const int* __restrict__ blocksums) {
    int i = blockIdx.x * SCAN_B + threadIdx.x;
    if (i < N_NODES) {
        int o = offsets[i] + blocksums[blockIdx.x];
        offsets[i] = o;
        cursor[i]  = o;
    }
    if (i == 0) offsets[N_NODES] = N_EDGES;
}

// ---------------------------------------------------------------------------
// CSR build: compute edge score once, place (src, e) into dst-grouped slots
__global__ __launch_bounds__(256) void build_csr_kernel(
        const int* __restrict__ src, const int* __restrict__ dst,
        const float* __restrict__ az_src, const float* __restrict__ az_dst,
        int* __restrict__ cursor,
        int* __restrict__ src_sorted, float* __restrict__ e_sorted) {
    int i = blockIdx.x * 256 + threadIdx.x;
    if (i >= N_EDGES) return;
    int s = src[i], t = dst[i];
    float v = az_src[s] + az_dst[t];
    float e = v > 0.f ? v : LEAKY * v;
    int pos = atomicAdd(&cursor[t], 1);
    src_sorted[pos] = s;
    e_sorted[pos]   = e;
}

// ---------------------------------------------------------------------------
// fused per-node softmax + weighted aggregation. One wave per node, lane = dim.
__global__ __launch_bounds__(256) void node_fused_kernel(
        const int* __restrict__ offsets,
        const int* __restrict__ src_sorted, const float* __restrict__ e_sorted,
        const float* __restrict__ z, float* __restrict__ h) {
    int lane = threadIdx.x & 63;
    int w    = threadIdx.x >> 6;
    int t    = blockIdx.x * 4 + w;
    if (t >= N_NODES) return;
    int beg = offsets[t];
    int end = offsets[t + 1];

    // pass 1: max over this node's edges (lanes parallel over edges)
    float m = -INFINITY;
    for (int i = beg + lane; i < end; i += 64)
        m = fmaxf(m, e_sorted[i]);
    for (int off = 32; off > 0; off >>= 1)
        m = fmaxf(m, __shfl_xor(m, off, 64));

    // pass 2: sum of exp
    float ssum = 0.f;
    for (int i = beg + lane; i < end; i += 64)
        ssum += __expf(e_sorted[i] - m);
    for (int off = 32; off > 0; off >>= 1)
        ssum += __shfl_xor(ssum, off, 64);
    float inv = (end > beg) ? 1.f / ssum : 0.f;

    // pass 3: accumulate alpha * z[src] ; lane owns one output dim
    float acc = 0.f;
#pragma unroll 2
    for (int i = beg; i < end; ++i) {
        int   s  = src_sorted[i];                        // wave-uniform
        float al = __expf(e_sorted[i] - m) * inv;
        acc += al * z[(size_t)s * OUT_DIM + lane];       // coalesced 256B row
    }
    h[(size_t)t * OUT_DIM + lane] = acc;                 // isolated node -> 0
}

// ---------------------------------------------------------------------------
extern "C" void kernel_launch(void* const* d_in, const int* in_sizes, int n_in,
                              void* d_out, int out_size, void* d_ws, size_t ws_size,
                              hipStream_t stream) {
    const float* feat = (const float*)d_in[0];
    const int*   src  = (const int*)  d_in[1];
    const int*   dst  = (const int*)  d_in[2];
    const float* W    = (const float*)d_in[3];
    const float* a    = (const float*)d_in[4];
    float* h = (float*)d_out;

    // workspace layout (all 4-byte elems)
    float* z          = (float*)d_ws;                        // N*64
    float* az_src     = z + (size_t)N_NODES * OUT_DIM;
    float* az_dst     = az_src + N_NODES;
    int*   counts     = (int*)(az_dst + N_NODES);            // N
    int*   offsets    = counts + N_NODES;                    // N+1
    int*   cursor     = offsets + N_NODES + 1;               // N
    int*   blocksums  = cursor + N_NODES;                    // 64
    int*   src_sorted = blocksums + 64;                      // E
    float* e_sorted   = (float*)(src_sorted + N_EDGES);      // E

    hipMemsetAsync(counts, 0, sizeof(int) * N_NODES, stream);

    proj_kernel<<<N_NODES / 4, 256, 0, stream>>>(feat, W, a, z, az_src, az_dst);

    int eblocks = (N_EDGES + 255) / 256;
    hist_kernel<<<eblocks, 256, 0, stream>>>(dst, counts);

    scan1_kernel<<<SCAN_NB, SCAN_B, 0, stream>>>(counts, offsets, blocksums);
    scan2_kernel<<<1, 64, 0, stream>>>(blocksums);
    scan3_kernel<<<SCAN_NB, SCAN_B, 0, stream>>>(offsets, cursor, blocksums);

    build_csr_kernel<<<eblocks, 256, 0, stream>>>(src, dst, az_src, az_dst,
                                                  cursor, src_sorted, e_sorted);

    node_fused_kernel<<<(N_NODES + 3) / 4, 256, 0, stream>>>(
        offsets, src_sorted, e_sorted, z, h);
}